// Round 8
// baseline (2309.046 us; speedup 1.0000x reference)
//
#include <hip/hip_runtime.h>
#include <hip/hip_fp16.h>
#include <cstdint>
#include <cstddef>

#define T_STEPS 256
#define K_DIM 2048
#define NW 16            // 16 compute waves, 1024 threads, 4 waves/SIMD
#define NT_W 4           // ntiles (16 cols) per wave: 64 cols, 16*64 = 1024/block
#define REG_NT 2         // ntiles per wave in VGPRs (32 VGPR)
#define LDS_NT 2         // ntiles per wave in LDS (128 KB total)

typedef _Float16 f16;
typedef _Float16 f16x8 __attribute__((ext_vector_type(8)));
typedef _Float16 f16x4 __attribute__((ext_vector_type(4)));
typedef _Float16 f16x2 __attribute__((ext_vector_type(2)));
typedef float f32x4 __attribute__((ext_vector_type(4)));

// LDS layout (static: 1 block/CU)
#define W1S_OFF 0        // 16 waves * 2 nt * 4 ks * 64 lanes * 16B = 131072
#define U_OFF   131072   // u [2 group][32 rows][64 cols] f16 swizzled = 8192
#define Y_OFF   139264   // y [2 group][2 par][32 rows][64 cols] f16 = 16384
#define PB_OFF  155648   // predbuf f32[2 group][16 wave][32 row] = 4096
#define SMEM_BYTES 159744

// workspace layout (786432 B total)
#define W1P_BYTES (128 * 4 * 64 * 16)            // 524288: packed fp16 W1
#define MBOX_OFF  W1P_BYTES
#define MBOX_BYTES (256 * 2 * 2 * 32 * 8)        // [block][group][slot][32] u64 = 262144

// Pack W1 [128][2048] f32 row-major into fp16 MFMA-B-fragment layout:
// w1p[((ntile*4 + ks)*64 + lane)*8 + i] = W1[ks*32 + (lane>>4)*8 + i][ntile*16 + (lane&15)]
__global__ void __launch_bounds__(64) prepack_w1(const float* __restrict__ W1,
                                                 f16* __restrict__ w1p) {
  int blk = blockIdx.x;            // 0..511 = ntile*4 + ks
  int ntile = blk >> 2, ks = blk & 3;
  int lane = threadIdx.x;
  int col = ntile * 16 + (lane & 15);
  int kb = ks * 32 + ((lane >> 4) << 3);
  f16x8 pk;
#pragma unroll
  for (int i = 0; i < 8; ++i) pk[i] = (f16)W1[(size_t)(kb + i) * K_DIM + col];
  ((f16x8*)w1p)[(ntile * 4 + ks) * 64 + lane] = pk;
}

__global__ void __launch_bounds__(1024, 4)
__attribute__((amdgpu_waves_per_eu(4, 4)))
rnn_fused(const float* __restrict__ u, const float* __restrict__ y0,
          const f16* __restrict__ w1p, const float* __restrict__ b1,
          const float* __restrict__ w2, const float* __restrict__ b2,
          float* __restrict__ out, unsigned long long* mbox)
{
  __shared__ __align__(16) char smem[SMEM_BYTES];
  f16x8* w1s     = (f16x8*)(smem + W1S_OFF);
  float* predbuf = (float*)(smem + PB_OFF);   // [group][wave][32]

  const int tid = threadIdx.x, lane = tid & 63, wave = tid >> 6;
  const int b = blockIdx.x;
  const int jj_ = b >> 3;
  const int half = jj_ & 1;                 // which K-half of W1
  const int pair = ((b & 7) << 4) | (jj_ >> 1);
  const int partner = b ^ 8;
  const int row0 = pair * 64;
  const int colbase = half * 1024;
  const float b2v = b2[0];
  const f16x8* w1pv = (const f16x8*)w1p;
  const float TWO_L = 2.885390081777927f;   // 2*log2(e)

  // per-lane epilogue constants (4 ntiles = 64 cols per wave)
  float b1x[NT_W], w2v[NT_W];
#pragma unroll
  for (int nt = 0; nt < NT_W; ++nt) {
    int col = colbase + wave * 64 + nt * 16 + (lane & 15);
    b1x[nt] = TWO_L * b1[col];
    w2v[nt] = w2[col];
  }

  // Chalf in both comm waves (wave0 = group0 comm, wave1 = group1 comm)
  float Chalf = 0.f;
  if (wave < 2) {
    float s = 0.f;
#pragma unroll
    for (int i = 0; i < 16; ++i) s += w2[colbase + lane * 16 + i];
    s += __shfl_xor(s, 1);  s += __shfl_xor(s, 2);  s += __shfl_xor(s, 4);
    s += __shfl_xor(s, 8);  s += __shfl_xor(s, 16); s += __shfl_xor(s, 32);
    Chalf = s;
  }

  // resident W1: 2 ntiles/wave in VGPRs, 2 in LDS
  f16x8 w1r[REG_NT * 4];
#pragma unroll
  for (int nt = 0; nt < REG_NT; ++nt)
#pragma unroll
    for (int ks = 0; ks < 4; ++ks)
      w1r[nt * 4 + ks] = w1pv[((half * 64 + wave * 4 + nt) * 4 + ks) * 64 + lane];
#pragma unroll
  for (int i = 0; i < REG_NT * 4; ++i) asm volatile("" : "+v"(w1r[i]));
#pragma unroll
  for (int nt = 0; nt < LDS_NT; ++nt)
#pragma unroll
    for (int ks = 0; ks < 4; ++ks)
      w1s[((wave * LDS_NT + nt) * 4 + ks) * 64 + lane] =
          w1pv[((half * 64 + wave * 4 + REG_NT + nt) * 4 + ks) * 64 + lane];

  // ---- init: both groups' y0 -> y[g][0], u_0 -> U[g], prefetch u_1.
  //      1024 threads: 32 rows x 32 col-pairs (2 cols each). ----
  const int r_i = tid >> 5;                 // 0..31
  const int j0 = (tid & 31) * 2;            // 2 cols per thread
  const int sw_i = (r_i & 7) << 4;
  float2 upA, upB;                          // u_{t+1} prefetch, G0/G1
#pragma unroll
  for (int g = 0; g < 2; ++g) {
    int row = row0 + g * 32 + r_i;
    {
      float2 a = *(const float2*)(y0 + (size_t)row * 64 + j0);
      f16x2 pk; pk[0] = (f16)a.x; pk[1] = (f16)a.y;
      *(f16x2*)(smem + Y_OFF + (g * 2 + 0) * 4096 + ((r_i * 128 + j0 * 2) ^ sw_i)) = pk;
    }
    {
      float2 a = *(const float2*)(u + ((size_t)row * T_STEPS + 0) * 64 + j0);
      f16x2 pk; pk[0] = (f16)a.x; pk[1] = (f16)a.y;
      *(f16x2*)(smem + U_OFF + g * 4096 + ((r_i * 128 + j0 * 2) ^ sw_i)) = pk;
    }
    float2 p1 = *(const float2*)(u + ((size_t)row * T_STEPS + 1) * 64 + j0);
    if (g == 0) upA = p1; else upB = p1;
  }
  __syncthreads();   // X valid for t=0, both groups

  float contrib0 = 0.f, contrib1 = 0.f;   // contrib0 live in wave0, contrib1 in wave1

  // ===== region(g,t): ONE barrier (structure identical to the verified r7
  // version; only the wave decomposition changed).  Comm duty for group gp
  // is owned by wave gp (0 or 1) -> per-wave comm overhead halves. =====
  auto region = [&](int g, int t) {
    const int gp = g ^ 1;
    const int t_p = (g == 1) ? t : t - 1;   // step of previous phase's group
    const int par = t & 1;
    const int par_p = t_p & 1;
    const int cw = gp;                      // comm wave for group gp

    unsigned long long pv0 = 0;
    const unsigned long long* mb = nullptr;

    if (t_p >= 0) {
      // comm wave: finalize prev group's half-sum; post; early-issue poll load
      if (wave == cw && lane < 32) {
        float own = 0.f;
#pragma unroll
        for (int w = 0; w < NW; ++w) own += predbuf[gp * 512 + w * 32 + lane];
        float c = fmaf(-2.0f, own, Chalf);
        if (gp == 0) contrib0 = c; else contrib1 = c;
        unsigned long long val =
            ((unsigned long long)(unsigned)(t_p + 1) << 32) |
            (unsigned long long)__builtin_bit_cast(unsigned, c);
        __hip_atomic_store(&mbox[((size_t)((b * 2 + gp) * 2 + par_p)) * 32 + lane], val,
                           __ATOMIC_RELAXED, __HIP_MEMORY_SCOPE_AGENT);
        mb = &mbox[((size_t)((partner * 2 + gp) * 2 + par_p)) * 32 + lane];
        pv0 = __hip_atomic_load(mb, __ATOMIC_RELAXED, __HIP_MEMORY_SCOPE_AGENT);
        asm volatile("" : "+v"(pv0));   // anchor: issue now, consume post-GEMM
      }
      // tail for (gp, t_p): y-shift gp -> y[gp][par_p^1] (col0 excluded: the
      // publish writes it), U[gp] <- u_{t_p+1}, prefetch u_{t_p+2}
      {
        const char* yp = smem + Y_OFF + (gp * 2 + par_p) * 4096;
        char*       yn = smem + Y_OFF + (gp * 2 + (par_p ^ 1)) * 4096;
        f16 a1 = *(const f16*)(yp + ((r_i * 128 + j0 * 2) ^ sw_i));
        if (j0) {
          f16 a0 = *(const f16*)(yp + ((r_i * 128 + j0 * 2 - 2) ^ sw_i));
          f16x2 nw; nw[0] = a0; nw[1] = a1;
          *(f16x2*)(yn + ((r_i * 128 + j0 * 2) ^ sw_i)) = nw;
        } else {
          // col1 only (col0 = pred, written by publish this region)
          *(f16*)(yn + ((r_i * 128 + 2) ^ sw_i)) = a1;
        }
        if (t_p + 1 < T_STEPS) {
          float2 up = (gp == 0) ? upA : upB;
          f16x2 pk; pk[0] = (f16)up.x; pk[1] = (f16)up.y;
          *(f16x2*)(smem + U_OFF + gp * 4096 + ((r_i * 128 + j0 * 2) ^ sw_i)) = pk;
        }
        if (t_p + 2 < T_STEPS) {
          float2 p = *(const float2*)(
              u + ((size_t)(row0 + gp * 32 + r_i) * T_STEPS + (t_p + 2)) * 64 + j0);
          if (gp == 0) upA = p; else upB = p;
        }
      }
    }

    // ---- GEMM(g,t): A-fragments for 32 rows (u: ks0-1, y: ks2-3) ----
    const char* ubase = smem + U_OFF + g * 4096;
    const char* ybase = smem + Y_OFF + (g * 2 + par) * 4096;
    f16x8 af[2][4];
    {
      int koff = (lane >> 4) << 4;
#pragma unroll
      for (int mt = 0; mt < 2; ++mt) {
        int r = mt * 16 + (lane & 15);
        int base = r * 128 + koff, sw = (r & 7) << 4;
        af[mt][0] = *(const f16x8*)(ubase + (base ^ sw));
        af[mt][1] = *(const f16x8*)(ubase + ((base + 64) ^ sw));
        af[mt][2] = *(const f16x8*)(ybase + (base ^ sw));
        af[mt][3] = *(const f16x8*)(ybase + ((base + 64) ^ sw));
      }
    }

    auto mfma_nt = [&](int nt, f32x4* acc) {
      acc[0] = (f32x4){0.f, 0.f, 0.f, 0.f};
      acc[1] = (f32x4){0.f, 0.f, 0.f, 0.f};
      __builtin_amdgcn_s_setprio(1);
#pragma unroll
      for (int ks = 0; ks < 4; ++ks) {
        f16x8 bf = (nt < REG_NT)
                       ? w1r[nt * 4 + ks]
                       : w1s[((wave * LDS_NT + (nt - REG_NT)) * 4 + ks) * 64 + lane];
        acc[0] = __builtin_amdgcn_mfma_f32_16x16x32_f16(af[0][ks], bf, acc[0], 0, 0, 0);
        acc[1] = __builtin_amdgcn_mfma_f32_16x16x32_f16(af[1][ks], bf, acc[1], 0, 0, 0);
      }
      __builtin_amdgcn_s_setprio(0);
    };

    float predp[2][4];
#pragma unroll
    for (int mt = 0; mt < 2; ++mt)
#pragma unroll
      for (int jj = 0; jj < 4; ++jj) predp[mt][jj] = 0.f;

    // epilogue: S += w2 * rcp(1 + exp2(2L*s + 2L*b1))
    auto epi = [&](int nt, f32x4* acc) {
#pragma unroll
      for (int mt = 0; mt < 2; ++mt)
#pragma unroll
        for (int jj = 0; jj < 4; ++jj) {
          float e  = __builtin_amdgcn_exp2f(fmaf(TWO_L, acc[mt][jj], b1x[nt]));
          float rr = __builtin_amdgcn_rcpf(1.0f + e);
          predp[mt][jj] = fmaf(w2v[nt], rr, predp[mt][jj]);
        }
    };

    // pipelined GEMM/epilogue over 4 ntiles
    f32x4 accA[2], accB[2];
    mfma_nt(0, accA);
    mfma_nt(1, accB);
    epi(0, accA); mfma_nt(2, accA);
    epi(1, accB); mfma_nt(3, accB);
    epi(2, accA);
    epi(3, accB);

    // wave reduce over the 16 col-lanes -> per-row partials into predbuf[g]
#pragma unroll
    for (int mt = 0; mt < 2; ++mt)
#pragma unroll
      for (int jj = 0; jj < 4; ++jj) {
        float v = predp[mt][jj];
        v += __shfl_xor(v, 1); v += __shfl_xor(v, 2);
        v += __shfl_xor(v, 4); v += __shfl_xor(v, 8);
        if ((lane & 15) == 0)
          predbuf[g * 512 + wave * 32 + mt * 16 + ((lane >> 4) << 2) + jj] = v;
      }

    // ---- comm wave: publish pred(gp, t_p) — early load normally tagged ----
    if (t_p >= 0 && wave == cw && lane < 32) {
      const unsigned want = (unsigned)(t_p + 1);
      unsigned long long pv = pv0;
      while ((unsigned)(pv >> 32) != want)
        pv = __hip_atomic_load(mb, __ATOMIC_RELAXED, __HIP_MEMORY_SCOPE_AGENT);
      float pc = __builtin_bit_cast(float, (unsigned)(pv & 0xffffffffu));
      float ps = ((gp == 0) ? contrib0 : contrib1) + pc + b2v;
      if (t_p + 1 < T_STEPS)
        *(f16*)(smem + Y_OFF + (gp * 2 + ((t_p + 1) & 1)) * 4096 +
                ((lane * 128) ^ ((lane & 7) << 4))) = (f16)ps;
      if (half == 0)
        out[(size_t)(row0 + gp * 32 + lane) * T_STEPS + t_p] = ps;
    }
    __syncthreads();  // the ONE barrier: predbuf[g], y[gp] shift+col0, U all valid
  };
  // ========================================================================

  for (int t = 0; t < T_STEPS; ++t) {
    region(0, t);
    region(1, t);
  }

  // flush: G1 step 255 (owned by wave1; its sum/post/publish never ran in-loop)
  if (wave == 1 && lane < 32) {
    float own = 0.f;
#pragma unroll
    for (int w = 0; w < NW; ++w) own += predbuf[1 * 512 + w * 32 + lane];
    float c1 = fmaf(-2.0f, own, Chalf);
    unsigned long long val =
        ((unsigned long long)(unsigned)T_STEPS << 32) |
        (unsigned long long)__builtin_bit_cast(unsigned, c1);
    __hip_atomic_store(&mbox[((size_t)((b * 2 + 1) * 2 + 1)) * 32 + lane], val,
                       __ATOMIC_RELAXED, __HIP_MEMORY_SCOPE_AGENT);
    const unsigned want = (unsigned)T_STEPS;
    unsigned long long pv;
    const unsigned long long* mb =
        &mbox[((size_t)((partner * 2 + 1) * 2 + 1)) * 32 + lane];
    do {
      pv = __hip_atomic_load(mb, __ATOMIC_RELAXED, __HIP_MEMORY_SCOPE_AGENT);
    } while ((unsigned)(pv >> 32) != want);
    float pc = __builtin_bit_cast(float, (unsigned)(pv & 0xffffffffu));
    float ps = c1 + pc + b2v;
    if (half == 0)
      out[(size_t)(row0 + 32 + lane) * T_STEPS + (T_STEPS - 1)] = ps;
  }
}

extern "C" void kernel_launch(void* const* d_in, const int* in_sizes, int n_in,
                              void* d_out, int out_size, void* d_ws, size_t ws_size,
                              hipStream_t stream) {
  const float* u  = (const float*)d_in[0];
  const float* y0 = (const float*)d_in[1];
  const float* W1 = (const float*)d_in[2];
  const float* b1 = (const float*)d_in[3];
  const float* W2 = (const float*)d_in[4];
  const float* b2 = (const float*)d_in[5];

  f16* w1p = (f16*)d_ws;
  unsigned long long* mbox = (unsigned long long*)((char*)d_ws + MBOX_OFF);

  // mailboxes must be zero at every launch (stale tags from a previous graph
  // replay would alias this launch's tags)
  hipMemsetAsync((char*)d_ws + MBOX_OFF, 0, MBOX_BYTES, stream);

  prepack_w1<<<512, 64, 0, stream>>>(W1, w1p);

  rnn_fused<<<256, 1024, 0, stream>>>(u, y0, w1p, b1, W2, b2, (float*)d_out, mbox);
}

// Round 9
// 2196.980 us; speedup vs baseline: 1.0510x; 1.0510x over previous
//
#include <hip/hip_runtime.h>
#include <hip/hip_fp16.h>
#include <cstdint>
#include <cstddef>

#define T_STEPS 256
#define K_DIM 2048
#define NCW 8            // 8 compute waves, 512 threads (r8: 16 waves => spills)
#define NT_W 8           // ntiles (16 cols) per wave: 128 cols, 1024/block
#define REG_NT 4         // ntiles per wave in VGPRs (r5: 8 forces spills)
#define LDS_NT 4         // ntiles per wave in LDS (128 KB)

typedef _Float16 f16;
typedef _Float16 f16x8 __attribute__((ext_vector_type(8)));
typedef _Float16 f16x4 __attribute__((ext_vector_type(4)));
typedef _Float16 f16x2 __attribute__((ext_vector_type(2)));
typedef float f32x4 __attribute__((ext_vector_type(4)));

// LDS layout (static: 1 block/CU)
#define W1S_OFF 0        // 8 waves * 4 nt * 4 ks * 64 lanes * 16B = 131072
#define U_OFF   131072   // u [2 group][32 rows][64 cols] f16 swizzled = 8192
#define Y_OFF   139264   // y [2 group][2 par][32 rows][64 cols] f16 = 16384
#define PB_OFF  155648   // predbuf f32[2 group][8 wave][32 row] = 2048 (dbuf by group)
#define SMEM_BYTES 157696

// workspace layout (786432 B total)
#define W1P_BYTES (128 * 4 * 64 * 16)            // 524288: packed fp16 W1
#define MBOX_OFF  W1P_BYTES
#define MBOX_BYTES (256 * 2 * 2 * 32 * 8)        // [block][group][slot][32] u64 = 262144

// Pack W1 [128][2048] f32 row-major into fp16 MFMA-B-fragment layout:
// w1p[((ntile*4 + ks)*64 + lane)*8 + i] = W1[ks*32 + (lane>>4)*8 + i][ntile*16 + (lane&15)]
__global__ void __launch_bounds__(64) prepack_w1(const float* __restrict__ W1,
                                                 f16* __restrict__ w1p) {
  int blk = blockIdx.x;            // 0..511 = ntile*4 + ks
  int ntile = blk >> 2, ks = blk & 3;
  int lane = threadIdx.x;
  int col = ntile * 16 + (lane & 15);
  int kb = ks * 32 + ((lane >> 4) << 3);
  f16x8 pk;
#pragma unroll
  for (int i = 0; i < 8; ++i) pk[i] = (f16)W1[(size_t)(kb + i) * K_DIM + col];
  ((f16x8*)w1p)[(ntile * 4 + ks) * 64 + lane] = pk;
}

__global__ void __launch_bounds__(512, 2)
__attribute__((amdgpu_waves_per_eu(2, 2)))
rnn_fused(const float* __restrict__ u, const float* __restrict__ y0,
          const f16* __restrict__ w1p, const float* __restrict__ b1,
          const float* __restrict__ w2, const float* __restrict__ b2,
          float* __restrict__ out, unsigned long long* mbox)
{
  __shared__ __align__(16) char smem[SMEM_BYTES];
  f16x8* w1s     = (f16x8*)(smem + W1S_OFF);
  float* predbuf = (float*)(smem + PB_OFF);   // [group][wave][32]

  const int tid = threadIdx.x, lane = tid & 63, wave = tid >> 6;
  const int b = blockIdx.x;
  const int jj_ = b >> 3;
  const int half = jj_ & 1;                 // which K-half of W1
  const int pair = ((b & 7) << 4) | (jj_ >> 1);
  const int partner = b ^ 8;
  const int row0 = pair * 64;
  const int colbase = half * 1024;
  const float b2v = b2[0];
  const f16x8* w1pv = (const f16x8*)w1p;
  const float TWO_L = 2.885390081777927f;   // 2*log2(e)

  // distributed-comm lane roles: each wave owns rows [wave*4, wave*4+4)
  const int cpart = lane & 7;               // which wave-partial this lane sums
  const int crow  = wave * 4 + (lane >> 3); // row (valid for lane < 32)
  const bool cpost = (lane < 32) && (cpart == 0);   // 4 posting lanes per wave

  // per-lane epilogue constants
  float b1x[NT_W], w2v[NT_W];
#pragma unroll
  for (int nt = 0; nt < NT_W; ++nt) {
    int col = colbase + wave * 128 + nt * 16 + (lane & 15);
    b1x[nt] = TWO_L * b1[col];
    w2v[nt] = w2[col];
  }

  // Chalf = sum of w2 over this block's 1024 cols (ALL waves: comm is distributed)
  float Chalf;
  {
    float s = 0.f;
#pragma unroll
    for (int i = 0; i < 16; ++i) s += w2[colbase + lane * 16 + i];
    s += __shfl_xor(s, 1);  s += __shfl_xor(s, 2);  s += __shfl_xor(s, 4);
    s += __shfl_xor(s, 8);  s += __shfl_xor(s, 16); s += __shfl_xor(s, 32);
    Chalf = s;
  }

  // resident W1: 4 ntiles/wave in VGPRs, 4 in LDS
  f16x8 w1r[REG_NT * 4];
#pragma unroll
  for (int nt = 0; nt < REG_NT; ++nt)
#pragma unroll
    for (int ks = 0; ks < 4; ++ks)
      w1r[nt * 4 + ks] = w1pv[((half * 64 + wave * 8 + nt) * 4 + ks) * 64 + lane];
#pragma unroll
  for (int i = 0; i < REG_NT * 4; ++i) asm volatile("" : "+v"(w1r[i]));
#pragma unroll
  for (int nt = 0; nt < LDS_NT; ++nt)
#pragma unroll
    for (int ks = 0; ks < 4; ++ks)
      w1s[((wave * LDS_NT + nt) * 4 + ks) * 64 + lane] =
          w1pv[((half * 64 + wave * 8 + REG_NT + nt) * 4 + ks) * 64 + lane];

  // ---- init: both groups' y0 -> y[g][0] (col0 = y0[:,0] directly for t=0),
  //      u_0 -> U[g], prefetch u_1 into regs ----
  const int r_i = tid >> 4;                 // 0..31
  const int j0c = (tid & 15) * 4;           // 4 cols per thread
  const int sw_i = (r_i & 7) << 4;
  float4 upA, upB;                          // u_{t+1} prefetch, G0/G1
#pragma unroll
  for (int g = 0; g < 2; ++g) {
    int row = row0 + g * 32 + r_i;
    {
      float4 a = *(const float4*)(y0 + (size_t)row * 64 + j0c);
      f16x4 pk; pk[0] = (f16)a.x; pk[1] = (f16)a.y; pk[2] = (f16)a.z; pk[3] = (f16)a.w;
      *(f16x4*)(smem + Y_OFF + (g * 2 + 0) * 4096 + ((r_i * 128 + j0c * 2) ^ sw_i)) = pk;
    }
    {
      float4 a = *(const float4*)(u + ((size_t)row * T_STEPS + 0) * 64 + j0c);
      f16x4 pk; pk[0] = (f16)a.x; pk[1] = (f16)a.y; pk[2] = (f16)a.z; pk[3] = (f16)a.w;
      *(f16x4*)(smem + U_OFF + g * 4096 + ((r_i * 128 + j0c * 2) ^ sw_i)) = pk;
    }
    float4 p1 = *(const float4*)(u + ((size_t)row * T_STEPS + 1) * 64 + j0c);
    if (g == 0) upA = p1; else upB = p1;
  }
  __syncthreads();   // X valid for t=0, both groups

  // ===== region(g,t): ONE barrier; structure identical to the verified r7
  // version except comm is DISTRIBUTED: each wave sums/posts/publishes its
  // own 4 rows -> no straggler wave at the barrier. =====
  auto region = [&](int g, int t) {
    const int gp = g ^ 1;
    const int t_p = (g == 1) ? t : t - 1;   // step of previous phase's group
    const int par = t & 1;
    const int par_p = t_p & 1;

    unsigned long long pv0 = 0;
    const unsigned long long* mb = nullptr;
    float creg = 0.f;

    if (t_p >= 0) {
      // distributed comm: sum predbuf[gp] for own row; post; early-issue poll
      {
        float own = 0.f;
        if (lane < 32) own = predbuf[gp * 256 + cpart * 32 + crow];
        own += __shfl_xor(own, 1); own += __shfl_xor(own, 2); own += __shfl_xor(own, 4);
        if (cpost) {
          creg = fmaf(-2.0f, own, Chalf);
          unsigned long long val =
              ((unsigned long long)(unsigned)(t_p + 1) << 32) |
              (unsigned long long)__builtin_bit_cast(unsigned, creg);
          __hip_atomic_store(&mbox[((size_t)((b * 2 + gp) * 2 + par_p)) * 32 + crow], val,
                             __ATOMIC_RELAXED, __HIP_MEMORY_SCOPE_AGENT);
          mb = &mbox[((size_t)((partner * 2 + gp) * 2 + par_p)) * 32 + crow];
          pv0 = __hip_atomic_load(mb, __ATOMIC_RELAXED, __HIP_MEMORY_SCOPE_AGENT);
          asm volatile("" : "+v"(pv0));   // anchor: issue now, consume post-GEMM
        }
      }
      // tail for (gp, t_p): y-shift gp -> y[gp][par_p^1] (cols >=1 for the
      // j0c==0 thread -- col0 belongs to publish), U[gp] <- u_{t_p+1}, prefetch
      {
        const char* yp = smem + Y_OFF + (gp * 2 + par_p) * 4096;
        char*       yn = smem + Y_OFF + (gp * 2 + (par_p ^ 1)) * 4096;
        f16x4 chB = *(const f16x4*)(yp + ((r_i * 128 + j0c * 2) ^ sw_i));
        char* dst = yn + ((r_i * 128 + j0c * 2) ^ sw_i);
        if (j0c) {
          f16x4 nw;
          nw[0] = *(const f16*)(yp + ((r_i * 128 + j0c * 2 - 2) ^ sw_i));
          nw[1] = chB[0]; nw[2] = chB[1]; nw[3] = chB[2];
          *(f16x4*)dst = nw;
        } else {
          // cols 1..3 only (col0 = pred, written by publish this region)
          *(f16*)(dst + 2) = chB[0];
          f16x2 hi; hi[0] = chB[1]; hi[1] = chB[2];
          *(f16x2*)(dst + 4) = hi;
        }
        if (t_p + 1 < T_STEPS) {
          float4 up = (gp == 0) ? upA : upB;
          f16x4 pk; pk[0] = (f16)up.x; pk[1] = (f16)up.y; pk[2] = (f16)up.z; pk[3] = (f16)up.w;
          *(f16x4*)(smem + U_OFF + gp * 4096 + ((r_i * 128 + j0c * 2) ^ sw_i)) = pk;
        }
        if (t_p + 2 < T_STEPS) {
          float4 p = *(const float4*)(
              u + ((size_t)(row0 + gp * 32 + r_i) * T_STEPS + (t_p + 2)) * 64 + j0c);
          if (gp == 0) upA = p; else upB = p;
        }
      }
    }

    // ---- GEMM(g,t): A-fragments for 32 rows (u: ks0-1, y: ks2-3) ----
    const char* ubase = smem + U_OFF + g * 4096;
    const char* ybase = smem + Y_OFF + (g * 2 + par) * 4096;
    f16x8 af[2][4];
    {
      int koff = (lane >> 4) << 4;
#pragma unroll
      for (int mt = 0; mt < 2; ++mt) {
        int r = mt * 16 + (lane & 15);
        int base = r * 128 + koff, sw = (r & 7) << 4;
        af[mt][0] = *(const f16x8*)(ubase + (base ^ sw));
        af[mt][1] = *(const f16x8*)(ubase + ((base + 64) ^ sw));
        af[mt][2] = *(const f16x8*)(ybase + (base ^ sw));
        af[mt][3] = *(const f16x8*)(ybase + ((base + 64) ^ sw));
      }
    }

    auto mfma_nt = [&](int nt, f32x4* acc) {
      acc[0] = (f32x4){0.f, 0.f, 0.f, 0.f};
      acc[1] = (f32x4){0.f, 0.f, 0.f, 0.f};
      __builtin_amdgcn_s_setprio(1);
#pragma unroll
      for (int ks = 0; ks < 4; ++ks) {
        f16x8 bf = (nt < REG_NT)
                       ? w1r[nt * 4 + ks]
                       : w1s[((wave * LDS_NT + (nt - REG_NT)) * 4 + ks) * 64 + lane];
        acc[0] = __builtin_amdgcn_mfma_f32_16x16x32_f16(af[0][ks], bf, acc[0], 0, 0, 0);
        acc[1] = __builtin_amdgcn_mfma_f32_16x16x32_f16(af[1][ks], bf, acc[1], 0, 0, 0);
      }
      __builtin_amdgcn_s_setprio(0);
    };

    float predp[2][4];
#pragma unroll
    for (int mt = 0; mt < 2; ++mt)
#pragma unroll
      for (int jj = 0; jj < 4; ++jj) predp[mt][jj] = 0.f;

    // epilogue: S += w2 * rcp(1 + exp2(2L*s + 2L*b1))
    auto epi = [&](int nt, f32x4* acc) {
#pragma unroll
      for (int mt = 0; mt < 2; ++mt)
#pragma unroll
        for (int jj = 0; jj < 4; ++jj) {
          float e  = __builtin_amdgcn_exp2f(fmaf(TWO_L, acc[mt][jj], b1x[nt]));
          float rr = __builtin_amdgcn_rcpf(1.0f + e);
          predp[mt][jj] = fmaf(w2v[nt], rr, predp[mt][jj]);
        }
    };

    // pipelined GEMM/epilogue (accA: even nt, accB: odd nt)
    f32x4 accA[2], accB[2];
    mfma_nt(0, accA);
    mfma_nt(1, accB);
    epi(0, accA); mfma_nt(2, accA);
    epi(1, accB); mfma_nt(3, accB);
    epi(2, accA); mfma_nt(4, accA);
    epi(3, accB); mfma_nt(5, accB);
    epi(4, accA); mfma_nt(6, accA);
    epi(5, accB); mfma_nt(7, accB);
    epi(6, accA);
    epi(7, accB);

    // wave reduce over the 16 col-lanes -> per-row partials into predbuf[g]
#pragma unroll
    for (int mt = 0; mt < 2; ++mt)
#pragma unroll
      for (int jj = 0; jj < 4; ++jj) {
        float v = predp[mt][jj];
        v += __shfl_xor(v, 1); v += __shfl_xor(v, 2);
        v += __shfl_xor(v, 4); v += __shfl_xor(v, 8);
        if ((lane & 15) == 0)
          predbuf[g * 256 + wave * 32 + mt * 16 + ((lane >> 4) << 2) + jj] = v;
      }

    // ---- distributed publish: each posting lane finalizes its own row.
    //      Early load normally already tagged; LLC latency covered by GEMM ----
    if (t_p >= 0 && cpost) {
      const unsigned want = (unsigned)(t_p + 1);
      unsigned long long pv = pv0;
      while ((unsigned)(pv >> 32) != want)
        pv = __hip_atomic_load(mb, __ATOMIC_RELAXED, __HIP_MEMORY_SCOPE_AGENT);
      float pc = __builtin_bit_cast(float, (unsigned)(pv & 0xffffffffu));
      float ps = creg + pc + b2v;
      if (t_p + 1 < T_STEPS)
        *(f16*)(smem + Y_OFF + (gp * 2 + ((t_p + 1) & 1)) * 4096 +
                ((crow * 128) ^ ((crow & 7) << 4))) = (f16)ps;
      if (half == 0)
        out[(size_t)(row0 + gp * 32 + crow) * T_STEPS + t_p] = ps;
    }
    __syncthreads();  // the ONE barrier: predbuf[g], y[gp] shift+col0, U all valid
  };
  // ========================================================================

  for (int t = 0; t < T_STEPS; ++t) {
    region(0, t);
    region(1, t);
  }

  // flush: G1 step 255 (its predbuf was filled in the last region; its sum,
  // post and publish never ran in-loop).  Distributed like the in-loop comm.
  {
    float own = 0.f;
    if (lane < 32) own = predbuf[1 * 256 + cpart * 32 + crow];
    own += __shfl_xor(own, 1); own += __shfl_xor(own, 2); own += __shfl_xor(own, 4);
    if (cpost) {
      float c1 = fmaf(-2.0f, own, Chalf);
      unsigned long long val =
          ((unsigned long long)(unsigned)T_STEPS << 32) |
          (unsigned long long)__builtin_bit_cast(unsigned, c1);
      __hip_atomic_store(&mbox[((size_t)((b * 2 + 1) * 2 + 1)) * 32 + crow], val,
                         __ATOMIC_RELAXED, __HIP_MEMORY_SCOPE_AGENT);
      const unsigned want = (unsigned)T_STEPS;
      unsigned long long pv;
      const unsigned long long* mbf =
          &mbox[((size_t)((partner * 2 + 1) * 2 + 1)) * 32 + crow];
      do {
        pv = __hip_atomic_load(mbf, __ATOMIC_RELAXED, __HIP_MEMORY_SCOPE_AGENT);
      } while ((unsigned)(pv >> 32) != want);
      float pc = __builtin_bit_cast(float, (unsigned)(pv & 0xffffffffu));
      float ps = c1 + pc + b2v;
      if (half == 0)
        out[(size_t)(row0 + 32 + crow) * T_STEPS + (T_STEPS - 1)] = ps;
    }
  }
}

extern "C" void kernel_launch(void* const* d_in, const int* in_sizes, int n_in,
                              void* d_out, int out_size, void* d_ws, size_t ws_size,
                              hipStream_t stream) {
  const float* u  = (const float*)d_in[0];
  const float* y0 = (const float*)d_in[1];
  const float* W1 = (const float*)d_in[2];
  const float* b1 = (const float*)d_in[3];
  const float* W2 = (const float*)d_in[4];
  const float* b2 = (const float*)d_in[5];

  f16* w1p = (f16*)d_ws;
  unsigned long long* mbox = (unsigned long long*)((char*)d_ws + MBOX_OFF);

  // mailboxes must be zero at every launch (stale tags from a previous graph
  // replay would alias this launch's tags)
  hipMemsetAsync((char*)d_ws + MBOX_OFF, 0, MBOX_BYTES, stream);

  prepack_w1<<<512, 64, 0, stream>>>(W1, w1p);

  rnn_fused<<<256, 512, 0, stream>>>(u, y0, w1p, b1, W2, b2, (float*)d_out, mbox);
}

// Round 11
// 1758.287 us; speedup vs baseline: 1.3132x; 1.2495x over previous
//
#include <hip/hip_runtime.h>
#include <hip/hip_fp16.h>
#include <cstdint>
#include <cstddef>

#define T_STEPS 256
#define K_DIM 2048
#define NCW 8            // 8 compute waves, 512 threads (r8: 16 waves => spills)
#define NT_W 8           // ntiles (16 cols) per wave: 128 cols, 1024/block
#define REG_NT 4         // ntiles per wave in VGPRs (r5: 8 forces spills)
#define LDS_NT 4         // ntiles per wave in LDS (128 KB)

typedef _Float16 f16;
typedef _Float16 f16x8 __attribute__((ext_vector_type(8)));
typedef _Float16 f16x4 __attribute__((ext_vector_type(4)));
typedef _Float16 f16x2 __attribute__((ext_vector_type(2)));
typedef float f32x4 __attribute__((ext_vector_type(4)));

// LDS layout (static: 1 block/CU)
#define W1S_OFF 0        // 8 waves * 4 nt * 4 ks * 64 lanes * 16B = 131072
#define U_OFF   131072   // u [2 group][32 rows][64 cols] f16 swizzled = 8192
#define Y_OFF   139264   // y [2 group][2 par][32 rows][64 cols] f16 = 16384
#define PB_OFF  155648   // predbuf f32[2 group][8 wave][32 row] = 2048 (dbuf by group)
#define SMEM_BYTES 157696

// workspace layout (786432 B total)
#define W1P_BYTES (128 * 4 * 64 * 16)            // 524288: packed fp16 W1 (prescaled)
#define MBOX_OFF  W1P_BYTES
#define MBOX_BYTES (256 * 2 * 2 * 32 * 8)        // [block][group][slot][32] u64 = 262144

// Pack W1 [128][2048] f32 row-major into fp16 MFMA-B-fragment layout,
// PRESCALED by 2*log2(e) so the epilogue needs no scale fma:
// w1p[((ntile*4 + ks)*64 + lane)*8 + i] = 2L * W1[ks*32 + (lane>>4)*8 + i][ntile*16 + (lane&15)]
__global__ void __launch_bounds__(64) prepack_w1(const float* __restrict__ W1,
                                                 f16* __restrict__ w1p) {
  int blk = blockIdx.x;            // 0..511 = ntile*4 + ks
  int ntile = blk >> 2, ks = blk & 3;
  int lane = threadIdx.x;
  int col = ntile * 16 + (lane & 15);
  int kb = ks * 32 + ((lane >> 4) << 3);
  const float TWO_L = 2.885390081777927f;
  f16x8 pk;
#pragma unroll
  for (int i = 0; i < 8; ++i) pk[i] = (f16)(TWO_L * W1[(size_t)(kb + i) * K_DIM + col]);
  ((f16x8*)w1p)[(ntile * 4 + ks) * 64 + lane] = pk;
}

__global__ void __launch_bounds__(512, 2)
__attribute__((amdgpu_waves_per_eu(2, 2)))
rnn_fused(const float* __restrict__ u, const float* __restrict__ y0,
          const f16* __restrict__ w1p, const float* __restrict__ b1,
          const float* __restrict__ w2, const float* __restrict__ b2,
          float* __restrict__ out, unsigned long long* mbox)
{
  __shared__ __align__(16) char smem[SMEM_BYTES];
  f16x8* w1s     = (f16x8*)(smem + W1S_OFF);
  float* predbuf = (float*)(smem + PB_OFF);   // [group][wave][32]

  const int tid = threadIdx.x, lane = tid & 63, wave = tid >> 6;
  const int b = blockIdx.x;
  const int jj_ = b >> 3;
  const int half = jj_ & 1;                 // which K-half of W1
  const int pair = ((b & 7) << 4) | (jj_ >> 1);
  const int partner = b ^ 8;
  const int row0 = pair * 64;
  const int colbase = half * 1024;
  const float b2v = b2[0];
  const f16x8* w1pv = (const f16x8*)w1p;
  const float TWO_L = 2.885390081777927f;   // 2*log2(e)

  // per-lane epilogue constants: bias rides in the MFMA C-operand (biasr);
  // acc then = 2L*(x.W1) + 2L*b1 directly (W1 prescaled in prepack)
  f32x4 biasr[NT_W];
  float w2v[NT_W];
#pragma unroll
  for (int nt = 0; nt < NT_W; ++nt) {
    int col = colbase + wave * 128 + nt * 16 + (lane & 15);
    float bv = TWO_L * b1[col];
    biasr[nt] = (f32x4){bv, bv, bv, bv};
    w2v[nt] = w2[col];
  }

  // Chalf = sum of w2 over this block's 1024 cols (wave 0, register-resident)
  float Chalf = 0.f;
  if (wave == 0) {
    float s = 0.f;
#pragma unroll
    for (int i = 0; i < 16; ++i) s += w2[colbase + lane * 16 + i];
    s += __shfl_xor(s, 1);  s += __shfl_xor(s, 2);  s += __shfl_xor(s, 4);
    s += __shfl_xor(s, 8);  s += __shfl_xor(s, 16); s += __shfl_xor(s, 32);
    Chalf = s;
  }

  // resident W1: 4 ntiles/wave in VGPRs, 4 in LDS
  f16x8 w1r[REG_NT * 4];
#pragma unroll
  for (int nt = 0; nt < REG_NT; ++nt)
#pragma unroll
    for (int ks = 0; ks < 4; ++ks)
      w1r[nt * 4 + ks] = w1pv[((half * 64 + wave * 8 + nt) * 4 + ks) * 64 + lane];
#pragma unroll
  for (int i = 0; i < REG_NT * 4; ++i) asm volatile("" : "+v"(w1r[i]));
#pragma unroll
  for (int nt = 0; nt < LDS_NT; ++nt)
#pragma unroll
    for (int ks = 0; ks < 4; ++ks)
      w1s[((wave * LDS_NT + nt) * 4 + ks) * 64 + lane] =
          w1pv[((half * 64 + wave * 8 + REG_NT + nt) * 4 + ks) * 64 + lane];

  // ---- init: both groups' y0 -> y[g][0] (col0 = y0[:,0] directly for t=0),
  //      u_0 -> U[g], prefetch u_1 into regs ----
  const int r_i = tid >> 4;                 // 0..31
  const int j0c = (tid & 15) * 4;           // 4 cols per thread
  const int sw_i = (r_i & 7) << 4;
  float4 upA, upB;                          // u_{t+1} prefetch, G0/G1
#pragma unroll
  for (int g = 0; g < 2; ++g) {
    int row = row0 + g * 32 + r_i;
    {
      float4 a = *(const float4*)(y0 + (size_t)row * 64 + j0c);
      f16x4 pk; pk[0] = (f16)a.x; pk[1] = (f16)a.y; pk[2] = (f16)a.z; pk[3] = (f16)a.w;
      *(f16x4*)(smem + Y_OFF + (g * 2 + 0) * 4096 + ((r_i * 128 + j0c * 2) ^ sw_i)) = pk;
    }
    {
      float4 a = *(const float4*)(u + ((size_t)row * T_STEPS + 0) * 64 + j0c);
      f16x4 pk; pk[0] = (f16)a.x; pk[1] = (f16)a.y; pk[2] = (f16)a.z; pk[3] = (f16)a.w;
      *(f16x4*)(smem + U_OFF + g * 4096 + ((r_i * 128 + j0c * 2) ^ sw_i)) = pk;
    }
    float4 p1 = *(const float4*)(u + ((size_t)row * T_STEPS + 1) * 64 + j0c);
    if (g == 0) upA = p1; else upB = p1;
  }
  __syncthreads();   // X valid for t=0, both groups

  float contrib0 = 0.f, contrib1 = 0.f;   // wave0: own half-sums per group

  // ===== region(g,t): ONE barrier; byte-identical structure to the verified
  // r7 champion (wave0 owns comm).  Arithmetic deltas vs r7: W1 prescaled in
  // prepack (no scale-fma) and bias seeded via the MFMA C-operand (no acc
  // zero-init).  Epilogue stays pure intrinsics (r10's inline VOP3P asm
  // produced NaN -- never again). =====
  auto region = [&](int g, int t) {
    const int gp = g ^ 1;
    const int t_p = (g == 1) ? t : t - 1;   // step of previous phase's group
    const int par = t & 1;
    const int par_p = t_p & 1;

    unsigned long long pv0 = 0;
    const unsigned long long* mb = nullptr;

    if (t_p >= 0) {
      // wave0: finalize previous group's half-sum; post; early-issue poll load
      if (wave == 0 && lane < 32) {
        float own = 0.f;
#pragma unroll
        for (int w = 0; w < NCW; ++w) own += predbuf[gp * 256 + w * 32 + lane];
        float c = fmaf(-2.0f, own, Chalf);
        if (gp == 0) contrib0 = c; else contrib1 = c;
        unsigned long long val =
            ((unsigned long long)(unsigned)(t_p + 1) << 32) |
            (unsigned long long)__builtin_bit_cast(unsigned, c);
        __hip_atomic_store(&mbox[((size_t)((b * 2 + gp) * 2 + par_p)) * 32 + lane], val,
                           __ATOMIC_RELAXED, __HIP_MEMORY_SCOPE_AGENT);
        mb = &mbox[((size_t)((partner * 2 + gp) * 2 + par_p)) * 32 + lane];
        pv0 = __hip_atomic_load(mb, __ATOMIC_RELAXED, __HIP_MEMORY_SCOPE_AGENT);
        asm volatile("" : "+v"(pv0));   // anchor: issue now, consume post-GEMM
      }
      // tail for (gp, t_p): y-shift gp -> y[gp][par_p^1] (cols >=1 for the
      // j0c==0 thread -- col0 belongs to publish), U[gp] <- u_{t_p+1}, prefetch
      {
        const char* yp = smem + Y_OFF + (gp * 2 + par_p) * 4096;
        char*       yn = smem + Y_OFF + (gp * 2 + (par_p ^ 1)) * 4096;
        f16x4 chB = *(const f16x4*)(yp + ((r_i * 128 + j0c * 2) ^ sw_i));
        char* dst = yn + ((r_i * 128 + j0c * 2) ^ sw_i);
        if (j0c) {
          f16x4 nw;
          nw[0] = *(const f16*)(yp + ((r_i * 128 + j0c * 2 - 2) ^ sw_i));
          nw[1] = chB[0]; nw[2] = chB[1]; nw[3] = chB[2];
          *(f16x4*)dst = nw;
        } else {
          // cols 1..3 only (col0 = pred, written by publish this region)
          *(f16*)(dst + 2) = chB[0];
          f16x2 hi; hi[0] = chB[1]; hi[1] = chB[2];
          *(f16x2*)(dst + 4) = hi;
        }
        if (t_p + 1 < T_STEPS) {
          float4 up = (gp == 0) ? upA : upB;
          f16x4 pk; pk[0] = (f16)up.x; pk[1] = (f16)up.y; pk[2] = (f16)up.z; pk[3] = (f16)up.w;
          *(f16x4*)(smem + U_OFF + gp * 4096 + ((r_i * 128 + j0c * 2) ^ sw_i)) = pk;
        }
        if (t_p + 2 < T_STEPS) {
          float4 p = *(const float4*)(
              u + ((size_t)(row0 + gp * 32 + r_i) * T_STEPS + (t_p + 2)) * 64 + j0c);
          if (gp == 0) upA = p; else upB = p;
        }
      }
    }

    // ---- GEMM(g,t): A-fragments for 32 rows (u: ks0-1, y: ks2-3) ----
    const char* ubase = smem + U_OFF + g * 4096;
    const char* ybase = smem + Y_OFF + (g * 2 + par) * 4096;
    f16x8 af[2][4];
    {
      int koff = (lane >> 4) << 4;
#pragma unroll
      for (int mt = 0; mt < 2; ++mt) {
        int r = mt * 16 + (lane & 15);
        int base = r * 128 + koff, sw = (r & 7) << 4;
        af[mt][0] = *(const f16x8*)(ubase + (base ^ sw));
        af[mt][1] = *(const f16x8*)(ubase + ((base + 64) ^ sw));
        af[mt][2] = *(const f16x8*)(ybase + (base ^ sw));
        af[mt][3] = *(const f16x8*)(ybase + ((base + 64) ^ sw));
      }
    }

    // ks=0 seeds the accumulator with the bias (C-operand); no zero-init movs
    auto mfma_nt = [&](int nt, f32x4* acc) {
      __builtin_amdgcn_s_setprio(1);
      {
        f16x8 bf0 = (nt < REG_NT)
                        ? w1r[nt * 4 + 0]
                        : w1s[((wave * LDS_NT + (nt - REG_NT)) * 4 + 0) * 64 + lane];
        acc[0] = __builtin_amdgcn_mfma_f32_16x16x32_f16(af[0][0], bf0, biasr[nt], 0, 0, 0);
        acc[1] = __builtin_amdgcn_mfma_f32_16x16x32_f16(af[1][0], bf0, biasr[nt], 0, 0, 0);
      }
#pragma unroll
      for (int ks = 1; ks < 4; ++ks) {
        f16x8 bf = (nt < REG_NT)
                       ? w1r[nt * 4 + ks]
                       : w1s[((wave * LDS_NT + (nt - REG_NT)) * 4 + ks) * 64 + lane];
        acc[0] = __builtin_amdgcn_mfma_f32_16x16x32_f16(af[0][ks], bf, acc[0], 0, 0, 0);
        acc[1] = __builtin_amdgcn_mfma_f32_16x16x32_f16(af[1][ks], bf, acc[1], 0, 0, 0);
      }
      __builtin_amdgcn_s_setprio(0);
    };

    float predp[2][4];
#pragma unroll
    for (int mt = 0; mt < 2; ++mt)
#pragma unroll
      for (int jj = 0; jj < 4; ++jj) predp[mt][jj] = 0.f;

    // epilogue: acc already = 2L*(x.W1 + b1).
    // e = exp2(acc); S += w2 * rcp(1 + e)
    auto epi = [&](int nt, f32x4* acc) {
#pragma unroll
      for (int mt = 0; mt < 2; ++mt)
#pragma unroll
        for (int jj = 0; jj < 4; ++jj) {
          float e  = __builtin_amdgcn_exp2f(acc[mt][jj]);
          float rr = __builtin_amdgcn_rcpf(1.0f + e);
          predp[mt][jj] = fmaf(w2v[nt], rr, predp[mt][jj]);
        }
    };

    // pipelined GEMM/epilogue (accA: even nt, accB: odd nt)
    f32x4 accA[2], accB[2];
    mfma_nt(0, accA);
    mfma_nt(1, accB);
    epi(0, accA); mfma_nt(2, accA);
    epi(1, accB); mfma_nt(3, accB);
    epi(2, accA); mfma_nt(4, accA);
    epi(3, accB); mfma_nt(5, accB);
    epi(4, accA); mfma_nt(6, accA);
    epi(5, accB); mfma_nt(7, accB);
    epi(6, accA);
    epi(7, accB);

    // wave reduce over the 16 col-lanes -> per-row partials into predbuf[g]
#pragma unroll
    for (int mt = 0; mt < 2; ++mt)
#pragma unroll
      for (int jj = 0; jj < 4; ++jj) {
        float v = predp[mt][jj];
        v += __shfl_xor(v, 1); v += __shfl_xor(v, 2);
        v += __shfl_xor(v, 4); v += __shfl_xor(v, 8);
        if ((lane & 15) == 0)
          predbuf[g * 256 + wave * 32 + mt * 16 + ((lane >> 4) << 2) + jj] = v;
      }

    // ---- wave0: publish pred(gp, t_p) — early load normally already tagged;
    //      LLC latency was covered by the GEMM above ----
    if (t_p >= 0 && wave == 0 && lane < 32) {
      const unsigned want = (unsigned)(t_p + 1);
      unsigned long long pv = pv0;
      while ((unsigned)(pv >> 32) != want)
        pv = __hip_atomic_load(mb, __ATOMIC_RELAXED, __HIP_MEMORY_SCOPE_AGENT);
      float pc = __builtin_bit_cast(float, (unsigned)(pv & 0xffffffffu));
      float ps = ((gp == 0) ? contrib0 : contrib1) + pc + b2v;
      if (t_p + 1 < T_STEPS)
        *(f16*)(smem + Y_OFF + (gp * 2 + ((t_p + 1) & 1)) * 4096 +
                ((lane * 128) ^ ((lane & 7) << 4))) = (f16)ps;
      if (half == 0)
        out[(size_t)(row0 + gp * 32 + lane) * T_STEPS + t_p] = ps;
    }
    __syncthreads();  // the ONE barrier: predbuf[g], y[gp] shift+col0, U all valid
  };
  // ========================================================================

  for (int t = 0; t < T_STEPS; ++t) {
    region(0, t);
    region(1, t);
  }

  // flush: G1 step 255 (its predbuf was filled in the last region; its sum,
  // post and publish never ran in-loop)
  if (wave == 0 && lane < 32) {
    float own = 0.f;
#pragma unroll
    for (int w = 0; w < NCW; ++w) own += predbuf[1 * 256 + w * 32 + lane];
    float c1 = fmaf(-2.0f, own, Chalf);
    unsigned long long val =
        ((unsigned long long)(unsigned)T_STEPS << 32) |
        (unsigned long long)__builtin_bit_cast(unsigned, c1);
    __hip_atomic_store(&mbox[((size_t)((b * 2 + 1) * 2 + 1)) * 32 + lane], val,
                       __ATOMIC_RELAXED, __HIP_MEMORY_SCOPE_AGENT);
    const unsigned want = (unsigned)T_STEPS;
    unsigned long long pv;
    const unsigned long long* mb =
        &mbox[((size_t)((partner * 2 + 1) * 2 + 1)) * 32 + lane];
    do {
      pv = __hip_atomic_load(mb, __ATOMIC_RELAXED, __HIP_MEMORY_SCOPE_AGENT);
    } while ((unsigned)(pv >> 32) != want);
    float pc = __builtin_bit_cast(float, (unsigned)(pv & 0xffffffffu));
    float ps = c1 + pc + b2v;
    if (half == 0)
      out[(size_t)(row0 + 32 + lane) * T_STEPS + (T_STEPS - 1)] = ps;
  }
}

extern "C" void kernel_launch(void* const* d_in, const int* in_sizes, int n_in,
                              void* d_out, int out_size, void* d_ws, size_t ws_size,
                              hipStream_t stream) {
  const float* u  = (const float*)d_in[0];
  const float* y0 = (const float*)d_in[1];
  const float* W1 = (const float*)d_in[2];
  const float* b1 = (const float*)d_in[3];
  const float* W2 = (const float*)d_in[4];
  const float* b2 = (const float*)d_in[5];

  f16* w1p = (f16*)d_ws;
  unsigned long long* mbox = (unsigned long long*)((char*)d_ws + MBOX_OFF);

  // mailboxes must be zero at every launch (stale tags from a previous graph
  // replay would alias this launch's tags)
  hipMemsetAsync((char*)d_ws + MBOX_OFF, 0, MBOX_BYTES, stream);

  prepack_w1<<<512, 64, 0, stream>>>(W1, w1p);

  rnn_fused<<<256, 512, 0, stream>>>(u, y0, w1p, b1, W2, b2, (float*)d_out, mbox);
}

// Round 12
// 1749.168 us; speedup vs baseline: 1.3201x; 1.0052x over previous
//
#include <hip/hip_runtime.h>
#include <hip/hip_fp16.h>
#include <cstdint>
#include <cstddef>

#define T_STEPS 256
#define K_DIM 2048
#define NCW 8            // 8 compute waves, 512 threads (r8: 16 waves => spills)
#define NT_W 8           // ntiles (16 cols) per wave: 128 cols, 1024/block
#define REG_NT 4         // ntiles per wave in VGPRs (r5: 8 forces spills)
#define LDS_NT 4         // ntiles per wave in LDS (128 KB)

typedef _Float16 f16;
typedef _Float16 f16x8 __attribute__((ext_vector_type(8)));
typedef _Float16 f16x4 __attribute__((ext_vector_type(4)));
typedef _Float16 f16x2 __attribute__((ext_vector_type(2)));
typedef float f32x4 __attribute__((ext_vector_type(4)));

// LDS layout (static: 1 block/CU)
#define W1S_OFF 0        // 8 waves * 4 nt * 4 ks * 64 lanes * 16B = 131072
#define U_OFF   131072   // u [2 group][32 rows][64 cols] f16 swizzled = 8192
#define Y_OFF   139264   // y [2 group][2 par][32 rows][64 cols] f16 = 16384
#define PB_OFF  155648   // predbuf f32[2 group][8 wave][32 row] = 2048 (dbuf by group)
#define SMEM_BYTES 157696

// workspace layout (786432 B total)
#define W1P_BYTES (128 * 4 * 64 * 16)            // 524288: packed fp16 W1 (prescaled)
#define MBOX_OFF  W1P_BYTES
#define MBOX_BYTES (256 * 2 * 2 * 32 * 8)        // [block][group][slot][32] u64 = 262144

// Pack W1 [128][2048] f32 row-major into fp16 MFMA-B-fragment layout,
// PRESCALED by 2*log2(e) so the epilogue needs no scale fma:
// w1p[((ntile*4 + ks)*64 + lane)*8 + i] = 2L * W1[ks*32 + (lane>>4)*8 + i][ntile*16 + (lane&15)]
__global__ void __launch_bounds__(64) prepack_w1(const float* __restrict__ W1,
                                                 f16* __restrict__ w1p) {
  int blk = blockIdx.x;            // 0..511 = ntile*4 + ks
  int ntile = blk >> 2, ks = blk & 3;
  int lane = threadIdx.x;
  int col = ntile * 16 + (lane & 15);
  int kb = ks * 32 + ((lane >> 4) << 3);
  const float TWO_L = 2.885390081777927f;
  f16x8 pk;
#pragma unroll
  for (int i = 0; i < 8; ++i) pk[i] = (f16)(TWO_L * W1[(size_t)(kb + i) * K_DIM + col]);
  ((f16x8*)w1p)[(ntile * 4 + ks) * 64 + lane] = pk;
}

__global__ void __launch_bounds__(512, 2)
__attribute__((amdgpu_waves_per_eu(2, 2)))
rnn_fused(const float* __restrict__ u, const float* __restrict__ y0,
          const f16* __restrict__ w1p, const float* __restrict__ b1,
          const float* __restrict__ w2, const float* __restrict__ b2,
          float* __restrict__ out, unsigned long long* mbox)
{
  __shared__ __align__(16) char smem[SMEM_BYTES];
  f16x8* w1s     = (f16x8*)(smem + W1S_OFF);
  float* predbuf = (float*)(smem + PB_OFF);   // [group][wave][32]

  const int tid = threadIdx.x, lane = tid & 63, wave = tid >> 6;
  const int b = blockIdx.x;
  const int jj_ = b >> 3;
  const int half = jj_ & 1;                 // which K-half of W1
  const int pair = ((b & 7) << 4) | (jj_ >> 1);
  const int partner = b ^ 8;
  const int row0 = pair * 64;
  const int colbase = half * 1024;
  const float b2v = b2[0];
  const f16x8* w1pv = (const f16x8*)w1p;
  const float TWO_L = 2.885390081777927f;   // 2*log2(e)

  // per-lane epilogue constants: bias rides in the MFMA C-operand (biasr);
  // acc then = 2L*(x.W1) + 2L*b1 directly (W1 prescaled in prepack)
  f32x4 biasr[NT_W];
  float w2v[NT_W];
#pragma unroll
  for (int nt = 0; nt < NT_W; ++nt) {
    int col = colbase + wave * 128 + nt * 16 + (lane & 15);
    float bv = TWO_L * b1[col];
    biasr[nt] = (f32x4){bv, bv, bv, bv};
    w2v[nt] = w2[col];
  }

  // Chalf = sum of w2 over this block's 1024 cols (waves 0 AND 1: comm split)
  float Chalf = 0.f;
  if (wave < 2) {
    float s = 0.f;
#pragma unroll
    for (int i = 0; i < 16; ++i) s += w2[colbase + lane * 16 + i];
    s += __shfl_xor(s, 1);  s += __shfl_xor(s, 2);  s += __shfl_xor(s, 4);
    s += __shfl_xor(s, 8);  s += __shfl_xor(s, 16); s += __shfl_xor(s, 32);
    Chalf = s;
  }

  // resident W1: 4 ntiles/wave in VGPRs, 4 in LDS
  f16x8 w1r[REG_NT * 4];
#pragma unroll
  for (int nt = 0; nt < REG_NT; ++nt)
#pragma unroll
    for (int ks = 0; ks < 4; ++ks)
      w1r[nt * 4 + ks] = w1pv[((half * 64 + wave * 8 + nt) * 4 + ks) * 64 + lane];
#pragma unroll
  for (int i = 0; i < REG_NT * 4; ++i) asm volatile("" : "+v"(w1r[i]));
#pragma unroll
  for (int nt = 0; nt < LDS_NT; ++nt)
#pragma unroll
    for (int ks = 0; ks < 4; ++ks)
      w1s[((wave * LDS_NT + nt) * 4 + ks) * 64 + lane] =
          w1pv[((half * 64 + wave * 8 + REG_NT + nt) * 4 + ks) * 64 + lane];

  // ---- init: both groups' y0 -> y[g][0] (col0 = y0[:,0] directly for t=0),
  //      u_0 -> U[g], prefetch u_1 into regs ----
  const int r_i = tid >> 4;                 // 0..31
  const int j0c = (tid & 15) * 4;           // 4 cols per thread
  const int sw_i = (r_i & 7) << 4;
  float4 upA, upB;                          // u_{t+1} prefetch, G0/G1
#pragma unroll
  for (int g = 0; g < 2; ++g) {
    int row = row0 + g * 32 + r_i;
    {
      float4 a = *(const float4*)(y0 + (size_t)row * 64 + j0c);
      f16x4 pk; pk[0] = (f16)a.x; pk[1] = (f16)a.y; pk[2] = (f16)a.z; pk[3] = (f16)a.w;
      *(f16x4*)(smem + Y_OFF + (g * 2 + 0) * 4096 + ((r_i * 128 + j0c * 2) ^ sw_i)) = pk;
    }
    {
      float4 a = *(const float4*)(u + ((size_t)row * T_STEPS + 0) * 64 + j0c);
      f16x4 pk; pk[0] = (f16)a.x; pk[1] = (f16)a.y; pk[2] = (f16)a.z; pk[3] = (f16)a.w;
      *(f16x4*)(smem + U_OFF + g * 4096 + ((r_i * 128 + j0c * 2) ^ sw_i)) = pk;
    }
    float4 p1 = *(const float4*)(u + ((size_t)row * T_STEPS + 1) * 64 + j0c);
    if (g == 0) upA = p1; else upB = p1;
  }
  __syncthreads();   // X valid for t=0, both groups

  float contrib0 = 0.f, contrib1 = 0.f;   // wave1: own half-sums per group

  // ===== region(g,t): ONE barrier; structure identical to the r11 champion
  // except comm is SPLIT with zero handoff: both waves 0,1 redundantly compute
  // the cheap 8-term sum; wave0 posts to mbox (top); wave1 early-issues the
  // partner load (top) and polls+publishes+stores (bottom).  Halves the
  // per-wave straggler and runs the two halves on different SIMDs. =====
  auto region = [&](int g, int t) {
    const int gp = g ^ 1;
    const int t_p = (g == 1) ? t : t - 1;   // step of previous phase's group
    const int par = t & 1;
    const int par_p = t_p & 1;

    unsigned long long pv0 = 0;
    const unsigned long long* mb = nullptr;

    if (t_p >= 0) {
      // waves 0,1: redundant sum of previous group's partials (no handoff)
      if (wave < 2 && lane < 32) {
        float own = 0.f;
#pragma unroll
        for (int w = 0; w < NCW; ++w) own += predbuf[gp * 256 + w * 32 + lane];
        float c = fmaf(-2.0f, own, Chalf);
        if (wave == 0) {
          // wave0: post own half-sum for the partner
          unsigned long long val =
              ((unsigned long long)(unsigned)(t_p + 1) << 32) |
              (unsigned long long)__builtin_bit_cast(unsigned, c);
          __hip_atomic_store(&mbox[((size_t)((b * 2 + gp) * 2 + par_p)) * 32 + lane], val,
                             __ATOMIC_RELAXED, __HIP_MEMORY_SCOPE_AGENT);
        } else {
          // wave1: keep contrib; early-issue the partner poll load
          if (gp == 0) contrib0 = c; else contrib1 = c;
          mb = &mbox[((size_t)((partner * 2 + gp) * 2 + par_p)) * 32 + lane];
          pv0 = __hip_atomic_load(mb, __ATOMIC_RELAXED, __HIP_MEMORY_SCOPE_AGENT);
          asm volatile("" : "+v"(pv0));   // anchor: issue now, consume post-GEMM
        }
      }
      // tail for (gp, t_p): y-shift gp -> y[gp][par_p^1] (cols >=1 for the
      // j0c==0 thread -- col0 belongs to publish), U[gp] <- u_{t_p+1}, prefetch
      {
        const char* yp = smem + Y_OFF + (gp * 2 + par_p) * 4096;
        char*       yn = smem + Y_OFF + (gp * 2 + (par_p ^ 1)) * 4096;
        f16x4 chB = *(const f16x4*)(yp + ((r_i * 128 + j0c * 2) ^ sw_i));
        char* dst = yn + ((r_i * 128 + j0c * 2) ^ sw_i);
        if (j0c) {
          f16x4 nw;
          nw[0] = *(const f16*)(yp + ((r_i * 128 + j0c * 2 - 2) ^ sw_i));
          nw[1] = chB[0]; nw[2] = chB[1]; nw[3] = chB[2];
          *(f16x4*)dst = nw;
        } else {
          // cols 1..3 only (col0 = pred, written by publish this region)
          *(f16*)(dst + 2) = chB[0];
          f16x2 hi; hi[0] = chB[1]; hi[1] = chB[2];
          *(f16x2*)(dst + 4) = hi;
        }
        if (t_p + 1 < T_STEPS) {
          float4 up = (gp == 0) ? upA : upB;
          f16x4 pk; pk[0] = (f16)up.x; pk[1] = (f16)up.y; pk[2] = (f16)up.z; pk[3] = (f16)up.w;
          *(f16x4*)(smem + U_OFF + gp * 4096 + ((r_i * 128 + j0c * 2) ^ sw_i)) = pk;
        }
        if (t_p + 2 < T_STEPS) {
          float4 p = *(const float4*)(
              u + ((size_t)(row0 + gp * 32 + r_i) * T_STEPS + (t_p + 2)) * 64 + j0c);
          if (gp == 0) upA = p; else upB = p;
        }
      }
    }

    // ---- GEMM(g,t): A-fragments for 32 rows (u: ks0-1, y: ks2-3) ----
    const char* ubase = smem + U_OFF + g * 4096;
    const char* ybase = smem + Y_OFF + (g * 2 + par) * 4096;
    f16x8 af[2][4];
    {
      int koff = (lane >> 4) << 4;
#pragma unroll
      for (int mt = 0; mt < 2; ++mt) {
        int r = mt * 16 + (lane & 15);
        int base = r * 128 + koff, sw = (r & 7) << 4;
        af[mt][0] = *(const f16x8*)(ubase + (base ^ sw));
        af[mt][1] = *(const f16x8*)(ubase + ((base + 64) ^ sw));
        af[mt][2] = *(const f16x8*)(ybase + (base ^ sw));
        af[mt][3] = *(const f16x8*)(ybase + ((base + 64) ^ sw));
      }
    }

    // ks=0 seeds the accumulator with the bias (C-operand); no zero-init movs
    auto mfma_nt = [&](int nt, f32x4* acc) {
      __builtin_amdgcn_s_setprio(1);
      {
        f16x8 bf0 = (nt < REG_NT)
                        ? w1r[nt * 4 + 0]
                        : w1s[((wave * LDS_NT + (nt - REG_NT)) * 4 + 0) * 64 + lane];
        acc[0] = __builtin_amdgcn_mfma_f32_16x16x32_f16(af[0][0], bf0, biasr[nt], 0, 0, 0);
        acc[1] = __builtin_amdgcn_mfma_f32_16x16x32_f16(af[1][0], bf0, biasr[nt], 0, 0, 0);
      }
#pragma unroll
      for (int ks = 1; ks < 4; ++ks) {
        f16x8 bf = (nt < REG_NT)
                       ? w1r[nt * 4 + ks]
                       : w1s[((wave * LDS_NT + (nt - REG_NT)) * 4 + ks) * 64 + lane];
        acc[0] = __builtin_amdgcn_mfma_f32_16x16x32_f16(af[0][ks], bf, acc[0], 0, 0, 0);
        acc[1] = __builtin_amdgcn_mfma_f32_16x16x32_f16(af[1][ks], bf, acc[1], 0, 0, 0);
      }
      __builtin_amdgcn_s_setprio(0);
    };

    float predp[2][4];
#pragma unroll
    for (int mt = 0; mt < 2; ++mt)
#pragma unroll
      for (int jj = 0; jj < 4; ++jj) predp[mt][jj] = 0.f;

    // epilogue: acc already = 2L*(x.W1 + b1).
    // e = exp2(acc); S += w2 * rcp(1 + e)
    auto epi = [&](int nt, f32x4* acc) {
#pragma unroll
      for (int mt = 0; mt < 2; ++mt)
#pragma unroll
        for (int jj = 0; jj < 4; ++jj) {
          float e  = __builtin_amdgcn_exp2f(acc[mt][jj]);
          float rr = __builtin_amdgcn_rcpf(1.0f + e);
          predp[mt][jj] = fmaf(w2v[nt], rr, predp[mt][jj]);
        }
    };

    // pipelined GEMM/epilogue (accA: even nt, accB: odd nt)
    f32x4 accA[2], accB[2];
    mfma_nt(0, accA);
    mfma_nt(1, accB);
    epi(0, accA); mfma_nt(2, accA);
    epi(1, accB); mfma_nt(3, accB);
    epi(2, accA); mfma_nt(4, accA);
    epi(3, accB); mfma_nt(5, accB);
    epi(4, accA); mfma_nt(6, accA);
    epi(5, accB); mfma_nt(7, accB);
    epi(6, accA);
    epi(7, accB);

    // wave reduce over the 16 col-lanes -> per-row partials into predbuf[g]
#pragma unroll
    for (int mt = 0; mt < 2; ++mt)
#pragma unroll
      for (int jj = 0; jj < 4; ++jj) {
        float v = predp[mt][jj];
        v += __shfl_xor(v, 1); v += __shfl_xor(v, 2);
        v += __shfl_xor(v, 4); v += __shfl_xor(v, 8);
        if ((lane & 15) == 0)
          predbuf[g * 256 + wave * 32 + mt * 16 + ((lane >> 4) << 2) + jj] = v;
      }

    // ---- wave1: publish pred(gp, t_p) — early load normally already tagged;
    //      LLC latency was covered by the GEMM above ----
    if (t_p >= 0 && wave == 1 && lane < 32) {
      const unsigned want = (unsigned)(t_p + 1);
      unsigned long long pv = pv0;
      while ((unsigned)(pv >> 32) != want)
        pv = __hip_atomic_load(mb, __ATOMIC_RELAXED, __HIP_MEMORY_SCOPE_AGENT);
      float pc = __builtin_bit_cast(float, (unsigned)(pv & 0xffffffffu));
      float ps = ((gp == 0) ? contrib0 : contrib1) + pc + b2v;
      if (t_p + 1 < T_STEPS)
        *(f16*)(smem + Y_OFF + (gp * 2 + ((t_p + 1) & 1)) * 4096 +
                ((lane * 128) ^ ((lane & 7) << 4))) = (f16)ps;
      if (half == 0)
        out[(size_t)(row0 + gp * 32 + lane) * T_STEPS + t_p] = ps;
    }
    __syncthreads();  // the ONE barrier: predbuf[g], y[gp] shift+col0, U all valid
  };
  // ========================================================================

  for (int t = 0; t < T_STEPS; ++t) {
    region(0, t);
    region(1, t);
  }

  // flush: G1 step 255 (its predbuf was filled in the last region; its sum,
  // post and publish never ran in-loop).  Same split: wave0 posts, wave1
  // polls + stores; both compute the sum redundantly.
  if (wave < 2 && lane < 32) {
    float own = 0.f;
#pragma unroll
    for (int w = 0; w < NCW; ++w) own += predbuf[1 * 256 + w * 32 + lane];
    float c1 = fmaf(-2.0f, own, Chalf);
    if (wave == 0) {
      unsigned long long val =
          ((unsigned long long)(unsigned)T_STEPS << 32) |
          (unsigned long long)__builtin_bit_cast(unsigned, c1);
      __hip_atomic_store(&mbox[((size_t)((b * 2 + 1) * 2 + 1)) * 32 + lane], val,
                         __ATOMIC_RELAXED, __HIP_MEMORY_SCOPE_AGENT);
    } else {
      const unsigned want = (unsigned)T_STEPS;
      unsigned long long pv;
      const unsigned long long* mbf =
          &mbox[((size_t)((partner * 2 + 1) * 2 + 1)) * 32 + lane];
      do {
        pv = __hip_atomic_load(mbf, __ATOMIC_RELAXED, __HIP_MEMORY_SCOPE_AGENT);
      } while ((unsigned)(pv >> 32) != want);
      float pc = __builtin_bit_cast(float, (unsigned)(pv & 0xffffffffu));
      float ps = c1 + pc + b2v;
      if (half == 0)
        out[(size_t)(row0 + 32 + lane) * T_STEPS + (T_STEPS - 1)] = ps;
    }
  }
}

extern "C" void kernel_launch(void* const* d_in, const int* in_sizes, int n_in,
                              void* d_out, int out_size, void* d_ws, size_t ws_size,
                              hipStream_t stream) {
  const float* u  = (const float*)d_in[0];
  const float* y0 = (const float*)d_in[1];
  const float* W1 = (const float*)d_in[2];
  const float* b1 = (const float*)d_in[3];
  const float* W2 = (const float*)d_in[4];
  const float* b2 = (const float*)d_in[5];

  f16* w1p = (f16*)d_ws;
  unsigned long long* mbox = (unsigned long long*)((char*)d_ws + MBOX_OFF);

  // mailboxes must be zero at every launch (stale tags from a previous graph
  // replay would alias this launch's tags)
  hipMemsetAsync((char*)d_ws + MBOX_OFF, 0, MBOX_BYTES, stream);

  prepack_w1<<<512, 64, 0, stream>>>(W1, w1p);

  rnn_fused<<<256, 512, 0, stream>>>(u, y0, w1p, b1, W2, b2, (float*)d_out, mbox);
}